// Round 1
// baseline (929.087 us; speedup 1.0000x reference)
//
#include <hip/hip_runtime.h>

typedef short  bfrag  __attribute__((ext_vector_type(8)));
typedef float  facc4  __attribute__((ext_vector_type(4)));
typedef unsigned short u16;
typedef unsigned int   u32;

#define MROWS 131072   // B*N = 256*512
#define DD    96

__device__ __forceinline__ u16 f2b(float f) {
  u32 u = __float_as_uint(f);
  return (u16)((u + 0x7FFFu + ((u >> 16) & 1u)) >> 16);   // RNE to bf16
}
__device__ __forceinline__ float b2f(u16 h) {
  return __uint_as_float(((u32)h) << 16);
}
__device__ __forceinline__ void splitf(float x, u16& h, u16& l) {
  h = f2b(x);
  l = f2b(x - b2f(h));
}
__device__ __forceinline__ void split4(float4 v, ushort4& oh, ushort4& ol) {
  splitf(v.x, oh.x, ol.x); splitf(v.y, oh.y, ol.y);
  splitf(v.z, oh.z, ol.z); splitf(v.w, oh.w, ol.w);
}

#define MFMA __builtin_amdgcn_mfma_f32_16x16x32_bf16

// ---------------- prep: split weights to hi/lo bf16, n-major; fold biases ------
__global__ void k_prep(const float* __restrict__ Wenc,
                       const float* __restrict__ benc,
                       const float* __restrict__ Wz0, const float* __restrict__ Wz1,
                       const float* __restrict__ Wr0, const float* __restrict__ Wr1,
                       const float* __restrict__ Wh0, const float* __restrict__ Wh1,
                       const float* __restrict__ bz0, const float* __restrict__ bz1,
                       const float* __restrict__ br0, const float* __restrict__ br1,
                       const float* __restrict__ bh0, const float* __restrict__ bh1,
                       u16* __restrict__ wencTh, u16* __restrict__ wencTl,
                       u16* __restrict__ wzrTh,  u16* __restrict__ wzrTl,
                       u16* __restrict__ whTh,   u16* __restrict__ whTl,
                       float* __restrict__ bias)
{
  int i = blockIdx.x * 256 + threadIdx.x;
  if (i < 36864) {                       // wencT [96][384] (K padded 300->384)
    int n = i / 384, k = i % 384;
    float v = (k < 300) ? Wenc[k * 96 + n] : 0.f;
    u16 h, l; splitf(v, h, l);
    wencTh[i] = h; wencTl[i] = l;
  } else if (i < 73728) {                // wzrT [2][96][192]: g=0 [Wz0;Wz1], g=1 [Wr0;Wr1]
    int j = i - 36864;
    int g = j / 18432, r = j % 18432;
    int n = r / 192, k = r % 192;
    const float* W0 = g ? Wr0 : Wz0;
    const float* W1 = g ? Wr1 : Wz1;
    float v = (k < 96) ? W0[k * 96 + n] : W1[(k - 96) * 96 + n];
    u16 h, l; splitf(v, h, l);
    wzrTh[j] = h; wzrTl[j] = l;
  } else if (i < 92160) {                // whT [96][192]: [Wh0;Wh1]
    int j = i - 73728;
    int n = j / 192, k = j % 192;
    float v = (k < 96) ? Wh0[k * 96 + n] : Wh1[(k - 96) * 96 + n];
    u16 h, l; splitf(v, h, l);
    whTh[j] = h; whTl[j] = l;
  } else if (i < 92544) {                // bias [4][96]: enc, z, r, h
    int j = i - 92160;
    int r = j / 96, n = j % 96;
    float v;
    if      (r == 0) v = benc[n];
    else if (r == 1) v = bz0[n] + bz1[n];
    else if (r == 2) v = br0[n] + br1[n];
    else             v = bh0[n] + bh1[n];
    bias[j] = v;
  }
}

// ---------------- encoder: xf = (mask*relu(x)) @ Wenc + benc  (fp32 out) -------
// Pipelined: double-buffered LDS (k-chunk 32), 1 barrier/chunk, loads issued
// one full chunk ahead of use.
__global__ __launch_bounds__(256) void k_enc(const float* __restrict__ x,
    const float* __restrict__ mask,
    const u16* __restrict__ wTh, const u16* __restrict__ wTl,
    const float* __restrict__ bias, float* __restrict__ xf)
{
  __shared__ u16 sAh[2][128][40], sAl[2][128][40];
  __shared__ u16 sBh[2][96][40],  sBl[2][96][40];
  const int tid = threadIdx.x;
  const int wave = tid >> 6, lane = tid & 63, q = lane >> 4, l15 = lane & 15;
  const int m0 = blockIdx.x * 128;
  const int arow = tid >> 1, ahf = tid & 1;
  const float mk = mask[m0 + arow];
  const float* xrow = x + (size_t)(m0 + arow) * 300 + ahf * 16;

  float4 Ra[4];
  uint4  Rb[3];

#define ENC_ISSUE_A(c) do { \
    int kb0 = (c) * 32; \
    _Pragma("unroll") \
    for (int j = 0; j < 4; ++j) { \
      int kk = kb0 + ahf * 16 + j * 4; \
      if (kk + 4 <= 300) Ra[j] = *(const float4*)(xrow + kb0 + j * 4); \
      else Ra[j] = make_float4(0.f, 0.f, 0.f, 0.f); \
    } } while (0)

#define ENC_ISSUE_B(c) do { \
    _Pragma("unroll") \
    for (int i = 0; i < 3; ++i) { \
      int idx = tid + 256 * i; \
      int half = idx >= 384; \
      int rr = idx - half * 384; \
      const u16* src = (half ? wTl : wTh) + (size_t)(rr >> 2) * 384 + (c) * 32 + (rr & 3) * 8; \
      Rb[i] = *(const uint4*)src; \
    } } while (0)

#define ENC_WRITE(b) do { \
    _Pragma("unroll") \
    for (int j = 0; j < 4; ++j) { \
      float4 v = Ra[j]; \
      v.x = fmaxf(v.x, 0.f) * mk; v.y = fmaxf(v.y, 0.f) * mk; \
      v.z = fmaxf(v.z, 0.f) * mk; v.w = fmaxf(v.w, 0.f) * mk; \
      ushort4 oh, ol; split4(v, oh, ol); \
      int kk = ahf * 16 + j * 4; \
      *(ushort4*)&sAh[b][arow][kk] = oh; \
      *(ushort4*)&sAl[b][arow][kk] = ol; \
    } \
    _Pragma("unroll") \
    for (int i = 0; i < 3; ++i) { \
      int idx = tid + 256 * i; \
      int half = idx >= 384; \
      int rr = idx - half * 384; \
      int n = rr >> 2, sg = rr & 3; \
      if (half) *(uint4*)&sBl[b][n][sg * 8] = Rb[i]; \
      else      *(uint4*)&sBh[b][n][sg * 8] = Rb[i]; \
    } } while (0)

  facc4 acc[2][6] = {};
  ENC_ISSUE_A(0); ENC_ISSUE_B(0);
  ENC_WRITE(0);
  ENC_ISSUE_A(1); ENC_ISSUE_B(1);
  __syncthreads();
  for (int c = 0; c < 10; ++c) {          // K = 320 (padded), chunks of 32
    int cur = c & 1;
    if (c < 9) {
      ENC_WRITE(cur ^ 1);                 // stage chunk c+1 into just-freed buf
      if (c < 8) { ENC_ISSUE_A(c + 2); ENC_ISSUE_B(c + 2); }
    }
    int kb = q * 8;
    bfrag a0h = *(const bfrag*)&sAh[cur][wave * 32 + l15][kb];
    bfrag a0l = *(const bfrag*)&sAl[cur][wave * 32 + l15][kb];
    bfrag a1h = *(const bfrag*)&sAh[cur][wave * 32 + 16 + l15][kb];
    bfrag a1l = *(const bfrag*)&sAl[cur][wave * 32 + 16 + l15][kb];
    #pragma unroll
    for (int nt = 0; nt < 6; ++nt) {
      bfrag bh = *(const bfrag*)&sBh[cur][nt * 16 + l15][kb];
      bfrag bl = *(const bfrag*)&sBl[cur][nt * 16 + l15][kb];
      acc[0][nt] = MFMA(a0h, bh, acc[0][nt], 0, 0, 0);
      acc[0][nt] = MFMA(a0h, bl, acc[0][nt], 0, 0, 0);
      acc[0][nt] = MFMA(a0l, bh, acc[0][nt], 0, 0, 0);
      acc[1][nt] = MFMA(a1h, bh, acc[1][nt], 0, 0, 0);
      acc[1][nt] = MFMA(a1h, bl, acc[1][nt], 0, 0, 0);
      acc[1][nt] = MFMA(a1l, bh, acc[1][nt], 0, 0, 0);
    }
    __syncthreads();
  }
  #pragma unroll
  for (int mt = 0; mt < 2; ++mt)
  #pragma unroll
  for (int rg = 0; rg < 4; ++rg) {
    int row = m0 + wave * 32 + mt * 16 + q * 4 + rg;
    #pragma unroll
    for (int nt = 0; nt < 6; ++nt) {
      int col = nt * 16 + l15;
      xf[(size_t)row * 96 + col] = acc[mt][nt][rg] + bias[col];
    }
  }
}

// ---------------- agg: af = adj @ xf  (batched, fp32 out; B transposed on the fly)
// Pipelined double-buffer (k-chunk 32); B tile [96][32] with 16B-granule XOR
// swizzle on the node offset -> transpose scalar writes go 8-way -> <=2-way.
__global__ __launch_bounds__(256) void k_agg(const float* __restrict__ adj,
    const float* __restrict__ xf, float* af)
{
  __shared__ u16 sAh[2][128][40], sAl[2][128][40];
  __shared__ u16 sBh[2][96][32],  sBl[2][96][32];
  const int tid = threadIdx.x;
  const int wave = tid >> 6, lane = tid & 63, q = lane >> 4, l15 = lane & 15;
  const int bb = blockIdx.y;
  const int m0 = blockIdx.x * 128;
  const float* A = adj + (size_t)bb * 512 * 512;
  const float* X = xf  + (size_t)bb * 512 * 96;
  const int arow = tid >> 1, ahf = tid & 1;
  const float* arp = A + (size_t)(m0 + arow) * 512 + ahf * 16;
  const int bnode = tid >> 3, bseg = tid & 7;
  const float* xp0 = X + (size_t)bnode * 96 + bseg * 12;

  float4 Ra[4], Rb[3];

#define AGG_ISSUE(c) do { \
    const float* ap = arp + (c) * 32; \
    _Pragma("unroll") for (int j = 0; j < 4; ++j) Ra[j] = *(const float4*)(ap + j * 4); \
    const float* xp = xp0 + (size_t)(c) * 32 * 96; \
    Rb[0] = *(const float4*)xp; \
    Rb[1] = *(const float4*)(xp + 4); \
    Rb[2] = *(const float4*)(xp + 8); } while (0)

#define AGG_PUT(b, d, h, l) do { \
    int off = (bnode * 2) ^ ((((d) >> 2) & 3) << 4); \
    *(u16*)((char*)&sBh[b][d][0] + off) = (h); \
    *(u16*)((char*)&sBl[b][d][0] + off) = (l); } while (0)

#define AGG_WRITE(b) do { \
    _Pragma("unroll") for (int j = 0; j < 4; ++j) { \
      ushort4 oh, ol; split4(Ra[j], oh, ol); \
      int kk = ahf * 16 + j * 4; \
      *(ushort4*)&sAh[b][arow][kk] = oh; \
      *(ushort4*)&sAl[b][arow][kk] = ol; } \
    _Pragma("unroll") for (int i = 0; i < 3; ++i) { \
      float4 v = Rb[i]; \
      int d0 = bseg * 12 + i * 4; \
      u16 h, l; \
      splitf(v.x, h, l); AGG_PUT(b, d0    , h, l); \
      splitf(v.y, h, l); AGG_PUT(b, d0 + 1, h, l); \
      splitf(v.z, h, l); AGG_PUT(b, d0 + 2, h, l); \
      splitf(v.w, h, l); AGG_PUT(b, d0 + 3, h, l); } } while (0)

  facc4 acc[2][6] = {};
  AGG_ISSUE(0); AGG_WRITE(0); AGG_ISSUE(1);
  __syncthreads();
  for (int c = 0; c < 16; ++c) {          // K = 512, chunks of 32
    int cur = c & 1;
    if (c < 15) {
      AGG_WRITE(cur ^ 1);
      if (c < 14) AGG_ISSUE(c + 2);
    }
    int kb = q * 8;
    bfrag a0h = *(const bfrag*)&sAh[cur][wave * 32 + l15][kb];
    bfrag a0l = *(const bfrag*)&sAl[cur][wave * 32 + l15][kb];
    bfrag a1h = *(const bfrag*)&sAh[cur][wave * 32 + 16 + l15][kb];
    bfrag a1l = *(const bfrag*)&sAl[cur][wave * 32 + 16 + l15][kb];
    #pragma unroll
    for (int nt = 0; nt < 6; ++nt) {
      int d = nt * 16 + l15;
      int off = (q * 16) ^ (((d >> 2) & 3) << 4);
      bfrag bh = *(const bfrag*)((const char*)&sBh[cur][d][0] + off);
      bfrag bl = *(const bfrag*)((const char*)&sBl[cur][d][0] + off);
      acc[0][nt] = MFMA(a0h, bh, acc[0][nt], 0, 0, 0);
      acc[0][nt] = MFMA(a0h, bl, acc[0][nt], 0, 0, 0);
      acc[0][nt] = MFMA(a0l, bh, acc[0][nt], 0, 0, 0);
      acc[1][nt] = MFMA(a1h, bh, acc[1][nt], 0, 0, 0);
      acc[1][nt] = MFMA(a1h, bl, acc[1][nt], 0, 0, 0);
      acc[1][nt] = MFMA(a1l, bh, acc[1][nt], 0, 0, 0);
    }
    __syncthreads();
  }
  #pragma unroll
  for (int mt = 0; mt < 2; ++mt)
  #pragma unroll
  for (int rg = 0; rg < 4; ++rg) {
    int row = m0 + wave * 32 + mt * 16 + q * 4 + rg;
    size_t grow = (size_t)bb * 512 + row;
    #pragma unroll
    for (int nt = 0; nt < 6; ++nt) {
      int col = nt * 16 + l15;
      af[grow * 96 + col] = acc[mt][nt][rg];
    }
  }
}

// ---------------- fused GRU ----------------------------------------------------
// GEMM1 computes az, ar AND the a@Wh0 part of ah (same A chunks, bit-identical
// accumulation order) -> GEMM2 is only rx@Wh1 read from LDS (no af re-read).
// LDS is a phase-union pool (67 KB vs 104 KB before). Issue-early/write-late
// staging.  af aliases d_out; outp aliases d_out; xf is read+written.
__global__ __launch_bounds__(256) void k_gru(const float* af, float* xf,
    const u16* __restrict__ wzrTh, const u16* __restrict__ wzrTl,
    const u16* __restrict__ whTh,  const u16* __restrict__ whTl,
    const float* __restrict__ bias, const float* __restrict__ mask,
    float* outp, const int last)
{
  // pool carve:
  //  GEMM1: sAh[128][40]@0  sAl@10240  sBh[288][40]@20480  sBl@43520  (66560)
  //  gates: sRxh[128][104]@0  sRxl@26624                              (53248)
  //  GEMM2: sB2h[96][40]@53248  sB2l@60928                            (68608)
  __shared__ __align__(16) char pool[68608];
  u16 (*sAh)[40]   = (u16(*)[40])(pool);
  u16 (*sAl)[40]   = (u16(*)[40])(pool + 10240);
  u16 (*sBh)[40]   = (u16(*)[40])(pool + 20480);   // rows: z 0-95, r 96-191, h0 192-287
  u16 (*sBl)[40]   = (u16(*)[40])(pool + 43520);
  u16 (*sRxh)[104] = (u16(*)[104])(pool);
  u16 (*sRxl)[104] = (u16(*)[104])(pool + 26624);
  u16 (*sB2h)[40]  = (u16(*)[40])(pool + 53248);
  u16 (*sB2l)[40]  = (u16(*)[40])(pool + 60928);

  const int tid = threadIdx.x;
  const int wave = tid >> 6, lane = tid & 63, q = lane >> 4, l15 = lane & 15;
  const int m0 = blockIdx.x * 128;
  const int arow = tid >> 1, ahf = tid & 1;

  float4 Ra[4];
  uint4  Rz[3], Rr[3];

#define GRU_ISSUE_A(c) do { \
    const float* base = ((c) < 3 ? af : xf) + (size_t)(m0 + arow) * 96 + ((c) % 3) * 32 + ahf * 16; \
    _Pragma("unroll") for (int j = 0; j < 4; ++j) Ra[j] = *(const float4*)(base + j * 4); \
  } while (0)

#define GRU_ISSUE_B(c) do { \
    int kw = (c) * 32; \
    _Pragma("unroll") for (int i = 0; i < 3; ++i) { \
      int idx = tid + 256 * i; \
      int half = idx >= 384; \
      int rr = idx - half * 384; \
      size_t o = (size_t)(rr >> 2) * 192 + kw + (rr & 3) * 8; \
      const u16* sb = half ? wzrTl : wzrTh; \
      Rz[i] = *(const uint4*)(sb + o); \
      Rr[i] = *(const uint4*)(sb + 18432 + o); \
    } } while (0)

#define GRU_WRITE_1(kw, withH) do { \
    _Pragma("unroll") for (int j = 0; j < 4; ++j) { \
      ushort4 oh, ol; split4(Ra[j], oh, ol); \
      int kk = ahf * 16 + j * 4; \
      *(ushort4*)&sAh[arow][kk] = oh; \
      *(ushort4*)&sAl[arow][kk] = ol; } \
    _Pragma("unroll") for (int i = 0; i < 3; ++i) { \
      int idx = tid + 256 * i; \
      int half = idx >= 384; \
      int rr = idx - half * 384; \
      int n = rr >> 2, sg = rr & 3; \
      if (half) { *(uint4*)&sBl[n][sg * 8] = Rz[i]; *(uint4*)&sBl[96 + n][sg * 8] = Rr[i]; } \
      else      { *(uint4*)&sBh[n][sg * 8] = Rz[i]; *(uint4*)&sBh[96 + n][sg * 8] = Rr[i]; } \
      if (withH) { \
        size_t o = (size_t)n * 192 + (kw) + sg * 8; \
        uint4 th = *(const uint4*)((half ? whTl : whTh) + o); \
        if (half) *(uint4*)&sBl[192 + n][sg * 8] = th; \
        else      *(uint4*)&sBh[192 + n][sg * 8] = th; \
      } } } while (0)

  // ---- GEMM1: az, ar over K=192; ah gets a@Wh0 for chunks 0..2 ----
  facc4 az[2][6] = {}, ar[2][6] = {}, ah[2][6] = {};
  GRU_ISSUE_A(0); GRU_ISSUE_B(0);
  GRU_WRITE_1(0, 1);
  __syncthreads();
  for (int c = 0; c < 6; ++c) {
    if (c < 5) { GRU_ISSUE_A(c + 1); GRU_ISSUE_B(c + 1); }
    int kb = q * 8;
    bfrag a0h = *(const bfrag*)&sAh[wave * 32 + l15][kb];
    bfrag a0l = *(const bfrag*)&sAl[wave * 32 + l15][kb];
    bfrag a1h = *(const bfrag*)&sAh[wave * 32 + 16 + l15][kb];
    bfrag a1l = *(const bfrag*)&sAl[wave * 32 + 16 + l15][kb];
    #pragma unroll
    for (int nt = 0; nt < 6; ++nt) {
      bfrag bh = *(const bfrag*)&sBh[nt * 16 + l15][kb];
      bfrag bl = *(const bfrag*)&sBl[nt * 16 + l15][kb];
      az[0][nt] = MFMA(a0h, bh, az[0][nt], 0, 0, 0);
      az[0][nt] = MFMA(a0h, bl, az[0][nt], 0, 0, 0);
      az[0][nt] = MFMA(a0l, bh, az[0][nt], 0, 0, 0);
      az[1][nt] = MFMA(a1h, bh, az[1][nt], 0, 0, 0);
      az[1][nt] = MFMA(a1h, bl, az[1][nt], 0, 0, 0);
      az[1][nt] = MFMA(a1l, bh, az[1][nt], 0, 0, 0);
      bfrag ch = *(const bfrag*)&sBh[96 + nt * 16 + l15][kb];
      bfrag cl = *(const bfrag*)&sBl[96 + nt * 16 + l15][kb];
      ar[0][nt] = MFMA(a0h, ch, ar[0][nt], 0, 0, 0);
      ar[0][nt] = MFMA(a0h, cl, ar[0][nt], 0, 0, 0);
      ar[0][nt] = MFMA(a0l, ch, ar[0][nt], 0, 0, 0);
      ar[1][nt] = MFMA(a1h, ch, ar[1][nt], 0, 0, 0);
      ar[1][nt] = MFMA(a1h, cl, ar[1][nt], 0, 0, 0);
      ar[1][nt] = MFMA(a1l, ch, ar[1][nt], 0, 0, 0);
    }
    if (c < 3) {
      #pragma unroll
      for (int nt = 0; nt < 6; ++nt) {
        bfrag dh = *(const bfrag*)&sBh[192 + nt * 16 + l15][kb];
        bfrag dl = *(const bfrag*)&sBl[192 + nt * 16 + l15][kb];
        ah[0][nt] = MFMA(a0h, dh, ah[0][nt], 0, 0, 0);
        ah[0][nt] = MFMA(a0h, dl, ah[0][nt], 0, 0, 0);
        ah[0][nt] = MFMA(a0l, dh, ah[0][nt], 0, 0, 0);
        ah[1][nt] = MFMA(a1h, dh, ah[1][nt], 0, 0, 0);
        ah[1][nt] = MFMA(a1h, dl, ah[1][nt], 0, 0, 0);
        ah[1][nt] = MFMA(a1l, dh, ah[1][nt], 0, 0, 0);
      }
    }
    __syncthreads();
    if (c < 5) { GRU_WRITE_1((c + 1) * 32, (c + 1) < 3); __syncthreads(); }
  }

  // ---- gates: z (kept fp32 in az), rx = sigmoid(ar+br)*x -> sRx (pool reuse) ----
  #pragma unroll
  for (int mt = 0; mt < 2; ++mt)
  #pragma unroll
  for (int rg = 0; rg < 4; ++rg) {
    int row = wave * 32 + mt * 16 + q * 4 + rg;
    int grow = m0 + row;
    #pragma unroll
    for (int nt = 0; nt < 6; ++nt) {
      int col = nt * 16 + l15;
      float vz = az[mt][nt][rg] + bias[96 + col];
      float vr = ar[mt][nt][rg] + bias[192 + col];
      float z = 1.f / (1.f + __expf(-vz));
      float r = 1.f / (1.f + __expf(-vr));
      az[mt][nt][rg] = z;
      float rx = r * xf[(size_t)grow * 96 + col];
      u16 h, l; splitf(rx, h, l);
      sRxh[row][col] = h;
      sRxl[row][col] = l;
    }
  }

  // ---- GEMM2: ah += rx @ Wh1 (A from LDS only; 3 chunks) ----
  uint4 R2[3];
#define GRU_ISSUE_B2(c) do { \
    _Pragma("unroll") for (int i = 0; i < 3; ++i) { \
      int idx = tid + 256 * i; \
      int half = idx >= 384; \
      int rr = idx - half * 384; \
      size_t o = (size_t)(rr >> 2) * 192 + 96 + (c) * 32 + (rr & 3) * 8; \
      R2[i] = *(const uint4*)((half ? whTl : whTh) + o); \
    } } while (0)
#define GRU_WRITE_B2() do { \
    _Pragma("unroll") for (int i = 0; i < 3; ++i) { \
      int idx = tid + 256 * i; \
      int half = idx >= 384; \
      int rr = idx - half * 384; \
      int n = rr >> 2, sg = rr & 3; \
      if (half) *(uint4*)&sB2l[n][sg * 8] = R2[i]; \
      else      *(uint4*)&sB2h[n][sg * 8] = R2[i]; \
    } } while (0)

  GRU_ISSUE_B2(0); GRU_WRITE_B2();
  __syncthreads();                        // publishes sRx + sB2
  for (int c = 0; c < 3; ++c) {
    if (c < 2) GRU_ISSUE_B2(c + 1);
    int kb = c * 32 + q * 8;
    bfrag a0h = *(const bfrag*)&sRxh[wave * 32 + l15][kb];
    bfrag a0l = *(const bfrag*)&sRxl[wave * 32 + l15][kb];
    bfrag a1h = *(const bfrag*)&sRxh[wave * 32 + 16 + l15][kb];
    bfrag a1l = *(const bfrag*)&sRxl[wave * 32 + 16 + l15][kb];
    #pragma unroll
    for (int nt = 0; nt < 6; ++nt) {
      bfrag bh = *(const bfrag*)&sB2h[nt * 16 + l15][q * 8];
      bfrag bl = *(const bfrag*)&sB2l[nt * 16 + l15][q * 8];
      ah[0][nt] = MFMA(a0h, bh, ah[0][nt], 0, 0, 0);
      ah[0][nt] = MFMA(a0h, bl, ah[0][nt], 0, 0, 0);
      ah[0][nt] = MFMA(a0l, bh, ah[0][nt], 0, 0, 0);
      ah[1][nt] = MFMA(a1h, bh, ah[1][nt], 0, 0, 0);
      ah[1][nt] = MFMA(a1h, bl, ah[1][nt], 0, 0, 0);
      ah[1][nt] = MFMA(a1l, bh, ah[1][nt], 0, 0, 0);
    }
    __syncthreads();
    if (c < 2) { GRU_WRITE_B2(); __syncthreads(); }
  }

  // ---- gate epilogue: out = x + z*(relu(mask*(h_pre+bh)) - x) ----
  #pragma unroll
  for (int mt = 0; mt < 2; ++mt)
  #pragma unroll
  for (int rg = 0; rg < 4; ++rg) {
    int row = m0 + wave * 32 + mt * 16 + q * 4 + rg;
    float mk = mask[row];
    #pragma unroll
    for (int nt = 0; nt < 6; ++nt) {
      int col = nt * 16 + l15;
      size_t idx = (size_t)row * 96 + col;
      float pre = ah[mt][nt][rg] + bias[288 + col];
      float hv  = fmaxf(mk * pre, 0.f);
      float zv  = az[mt][nt][rg];
      float xv  = xf[idx];
      float o   = xv + zv * (hv - xv);
      if (last) outp[idx] = o;
      else      xf[idx]   = o;
    }
  }
}

extern "C" void kernel_launch(void* const* d_in, const int* in_sizes, int n_in,
                              void* d_out, int out_size, void* d_ws, size_t ws_size,
                              hipStream_t stream)
{
  const float* x    = (const float*)d_in[0];
  const float* adj  = (const float*)d_in[1];
  const float* mask = (const float*)d_in[2];
  const float* Wenc = (const float*)d_in[3];
  const float* benc = (const float*)d_in[4];
  const float* Wz0  = (const float*)d_in[5];
  const float* Wz1  = (const float*)d_in[6];
  const float* Wr0  = (const float*)d_in[7];
  const float* Wr1  = (const float*)d_in[8];
  const float* Wh0  = (const float*)d_in[9];
  const float* Wh1  = (const float*)d_in[10];
  const float* bz0  = (const float*)d_in[11];
  const float* bz1  = (const float*)d_in[12];
  const float* br0  = (const float*)d_in[13];
  const float* br1  = (const float*)d_in[14];
  const float* bh0  = (const float*)d_in[15];
  const float* bh1  = (const float*)d_in[16];

  char* ws = (char*)d_ws;
  const size_t NEL = (size_t)MROWS * DD;            // 12,582,912
  float* xf   = (float*)(ws);                       // 50,331,648 B
  char*  wb   = ws + 4 * NEL;
  u16* wencTh = (u16*)(wb);                         // 73,728 B
  u16* wencTl = (u16*)(wb + 73728);
  u16* wzrTh  = (u16*)(wb + 147456);                // 73,728 B
  u16* wzrTl  = (u16*)(wb + 221184);
  u16* whTh   = (u16*)(wb + 294912);                // 36,864 B
  u16* whTl   = (u16*)(wb + 331776);
  float* bias = (float*)(wb + 368640);              // 1,536 B

  float* af   = (float*)d_out;                      // a-buffer aliases d_out
  float* outp = (float*)d_out;

  k_prep<<<362, 256, 0, stream>>>(Wenc, benc, Wz0, Wz1, Wr0, Wr1, Wh0, Wh1,
                                  bz0, bz1, br0, br1, bh0, bh1,
                                  wencTh, wencTl, wzrTh, wzrTl, whTh, whTl, bias);
  k_enc<<<dim3(MROWS / 128), 256, 0, stream>>>(x, mask, wencTh, wencTl, bias, xf);
  for (int s = 0; s < 2; ++s) {
    int last = (s == 1);
    k_agg<<<dim3(4, 256), 256, 0, stream>>>(adj, xf, af);
    k_gru<<<dim3(MROWS / 128), 256, 0, stream>>>(af, xf, wzrTh, wzrTl, whTh, whTl,
                                                 bias, mask, outp, last);
  }
}

// Round 2
// 895.163 us; speedup vs baseline: 1.0379x; 1.0379x over previous
//
#include <hip/hip_runtime.h>

typedef short  bfrag  __attribute__((ext_vector_type(8)));
typedef float  facc4  __attribute__((ext_vector_type(4)));
typedef unsigned short u16;
typedef unsigned int   u32;

#define MROWS 131072   // B*N = 256*512
#define DD    96

__device__ __forceinline__ u16 f2b(float f) {
  u32 u = __float_as_uint(f);
  return (u16)((u + 0x7FFFu + ((u >> 16) & 1u)) >> 16);   // RNE to bf16
}
__device__ __forceinline__ float b2f(u16 h) {
  return __uint_as_float(((u32)h) << 16);
}
__device__ __forceinline__ void splitf(float x, u16& h, u16& l) {
  h = f2b(x);
  l = f2b(x - b2f(h));
}
__device__ __forceinline__ void split4(float4 v, ushort4& oh, ushort4& ol) {
  splitf(v.x, oh.x, ol.x); splitf(v.y, oh.y, ol.y);
  splitf(v.z, oh.z, ol.z); splitf(v.w, oh.w, ol.w);
}

#define MFMA __builtin_amdgcn_mfma_f32_16x16x32_bf16

// ---------------- prep: split weights to hi/lo bf16, n-major; fold biases ------
__global__ void k_prep(const float* __restrict__ Wenc,
                       const float* __restrict__ benc,
                       const float* __restrict__ Wz0, const float* __restrict__ Wz1,
                       const float* __restrict__ Wr0, const float* __restrict__ Wr1,
                       const float* __restrict__ Wh0, const float* __restrict__ Wh1,
                       const float* __restrict__ bz0, const float* __restrict__ bz1,
                       const float* __restrict__ br0, const float* __restrict__ br1,
                       const float* __restrict__ bh0, const float* __restrict__ bh1,
                       u16* __restrict__ wencTh, u16* __restrict__ wencTl,
                       u16* __restrict__ wzrTh,  u16* __restrict__ wzrTl,
                       u16* __restrict__ whTh,   u16* __restrict__ whTl,
                       float* __restrict__ bias)
{
  int i = blockIdx.x * 256 + threadIdx.x;
  if (i < 36864) {                       // wencT [96][384] (K padded 300->384)
    int n = i / 384, k = i % 384;
    float v = (k < 300) ? Wenc[k * 96 + n] : 0.f;
    u16 h, l; splitf(v, h, l);
    wencTh[i] = h; wencTl[i] = l;
  } else if (i < 73728) {                // wzrT [2][96][192]: g=0 [Wz0;Wz1], g=1 [Wr0;Wr1]
    int j = i - 36864;
    int g = j / 18432, r = j % 18432;
    int n = r / 192, k = r % 192;
    const float* W0 = g ? Wr0 : Wz0;
    const float* W1 = g ? Wr1 : Wz1;
    float v = (k < 96) ? W0[k * 96 + n] : W1[(k - 96) * 96 + n];
    u16 h, l; splitf(v, h, l);
    wzrTh[j] = h; wzrTl[j] = l;
  } else if (i < 92160) {                // whT [96][192]: [Wh0;Wh1]
    int j = i - 73728;
    int n = j / 192, k = j % 192;
    float v = (k < 96) ? Wh0[k * 96 + n] : Wh1[(k - 96) * 96 + n];
    u16 h, l; splitf(v, h, l);
    whTh[j] = h; whTl[j] = l;
  } else if (i < 92544) {                // bias [4][96]: enc, z, r, h
    int j = i - 92160;
    int r = j / 96, n = j % 96;
    float v;
    if      (r == 0) v = benc[n];
    else if (r == 1) v = bz0[n] + bz1[n];
    else if (r == 2) v = br0[n] + br1[n];
    else             v = bh0[n] + bh1[n];
    bias[j] = v;
  }
}

// ---------------- encoder: xf = (mask*relu(x)) @ Wenc + benc  (fp32 out) -------
// Pipelined: double-buffered LDS (k-chunk 32), 1 barrier/chunk, loads issued
// one full chunk ahead of use.  A hi/lo merged in one [72]-wide array (hi@0,
// lo@40) -> LDS 67584 B declared (+12288 runtime overhead = 79872 <= 81920,
// keeps 2 blocks/CU).  launch_bounds(256,2): VGPR cap 256 matches the
// LDS-limited 2 waves/SIMD, prevents spill-for-unreachable-occupancy.
__global__ __launch_bounds__(256, 2) void k_enc(const float* __restrict__ x,
    const float* __restrict__ mask,
    const u16* __restrict__ wTh, const u16* __restrict__ wTl,
    const float* __restrict__ bias, float* __restrict__ xf)
{
  __shared__ u16 sA[2][128][72];          // hi cols 0..31, lo cols 40..71
  __shared__ u16 sBh[2][96][40], sBl[2][96][40];
  const int tid = threadIdx.x;
  const int wave = tid >> 6, lane = tid & 63, q = lane >> 4, l15 = lane & 15;
  const int m0 = blockIdx.x * 128;
  const int arow = tid >> 1, ahf = tid & 1;
  const float mk = mask[m0 + arow];
  const float* xrow = x + (size_t)(m0 + arow) * 300 + ahf * 16;

  float4 Ra[4];
  uint4  Rb[3];

#define ENC_ISSUE_A(c) do { \
    int kb0 = (c) * 32; \
    _Pragma("unroll") \
    for (int j = 0; j < 4; ++j) { \
      int kk = kb0 + ahf * 16 + j * 4; \
      if (kk + 4 <= 300) Ra[j] = *(const float4*)(xrow + kb0 + j * 4); \
      else Ra[j] = make_float4(0.f, 0.f, 0.f, 0.f); \
    } } while (0)

#define ENC_ISSUE_B(c) do { \
    _Pragma("unroll") \
    for (int i = 0; i < 3; ++i) { \
      int idx = tid + 256 * i; \
      int half = idx >= 384; \
      int rr = idx - half * 384; \
      const u16* src = (half ? wTl : wTh) + (size_t)(rr >> 2) * 384 + (c) * 32 + (rr & 3) * 8; \
      Rb[i] = *(const uint4*)src; \
    } } while (0)

#define ENC_WRITE(b) do { \
    _Pragma("unroll") \
    for (int j = 0; j < 4; ++j) { \
      float4 v = Ra[j]; \
      v.x = fmaxf(v.x, 0.f) * mk; v.y = fmaxf(v.y, 0.f) * mk; \
      v.z = fmaxf(v.z, 0.f) * mk; v.w = fmaxf(v.w, 0.f) * mk; \
      ushort4 oh, ol; split4(v, oh, ol); \
      int kk = ahf * 16 + j * 4; \
      *(ushort4*)&sA[b][arow][kk]      = oh; \
      *(ushort4*)&sA[b][arow][40 + kk] = ol; \
    } \
    _Pragma("unroll") \
    for (int i = 0; i < 3; ++i) { \
      int idx = tid + 256 * i; \
      int half = idx >= 384; \
      int rr = idx - half * 384; \
      int n = rr >> 2, sg = rr & 3; \
      if (half) *(uint4*)&sBl[b][n][sg * 8] = Rb[i]; \
      else      *(uint4*)&sBh[b][n][sg * 8] = Rb[i]; \
    } } while (0)

  facc4 acc[2][6] = {};
  ENC_ISSUE_A(0); ENC_ISSUE_B(0);
  ENC_WRITE(0);
  ENC_ISSUE_A(1); ENC_ISSUE_B(1);
  __syncthreads();
  for (int c = 0; c < 10; ++c) {          // K = 320 (padded), chunks of 32
    int cur = c & 1;
    if (c < 9) {
      ENC_WRITE(cur ^ 1);                 // stage chunk c+1 into just-freed buf
      if (c < 8) { ENC_ISSUE_A(c + 2); ENC_ISSUE_B(c + 2); }
    }
    int kb = q * 8;
    bfrag a0h = *(const bfrag*)&sA[cur][wave * 32 + l15][kb];
    bfrag a0l = *(const bfrag*)&sA[cur][wave * 32 + l15][40 + kb];
    bfrag a1h = *(const bfrag*)&sA[cur][wave * 32 + 16 + l15][kb];
    bfrag a1l = *(const bfrag*)&sA[cur][wave * 32 + 16 + l15][40 + kb];
    #pragma unroll
    for (int nt = 0; nt < 6; ++nt) {
      bfrag bh = *(const bfrag*)&sBh[cur][nt * 16 + l15][kb];
      bfrag bl = *(const bfrag*)&sBl[cur][nt * 16 + l15][kb];
      acc[0][nt] = MFMA(a0h, bh, acc[0][nt], 0, 0, 0);
      acc[0][nt] = MFMA(a0h, bl, acc[0][nt], 0, 0, 0);
      acc[0][nt] = MFMA(a0l, bh, acc[0][nt], 0, 0, 0);
      acc[1][nt] = MFMA(a1h, bh, acc[1][nt], 0, 0, 0);
      acc[1][nt] = MFMA(a1h, bl, acc[1][nt], 0, 0, 0);
      acc[1][nt] = MFMA(a1l, bh, acc[1][nt], 0, 0, 0);
    }
    __syncthreads();
  }
  #pragma unroll
  for (int mt = 0; mt < 2; ++mt)
  #pragma unroll
  for (int rg = 0; rg < 4; ++rg) {
    int row = m0 + wave * 32 + mt * 16 + q * 4 + rg;
    #pragma unroll
    for (int nt = 0; nt < 6; ++nt) {
      int col = nt * 16 + l15;
      xf[(size_t)row * 96 + col] = acc[mt][nt][rg] + bias[col];
    }
  }
}

// ---------------- agg: af = adj @ xf  (batched, fp32 out; B transposed on the fly)
// Pipelined double-buffer (k-chunk 32); B tile [96][32] with 16B-granule XOR
// swizzle on the node offset.  LDS 65536 (+12288 = 77824, 2 blocks/CU).
__global__ __launch_bounds__(256, 2) void k_agg(const float* __restrict__ adj,
    const float* __restrict__ xf, float* af)
{
  __shared__ u16 sAh[2][128][40], sAl[2][128][40];
  __shared__ u16 sBh[2][96][32],  sBl[2][96][32];
  const int tid = threadIdx.x;
  const int wave = tid >> 6, lane = tid & 63, q = lane >> 4, l15 = lane & 15;
  const int bb = blockIdx.y;
  const int m0 = blockIdx.x * 128;
  const float* A = adj + (size_t)bb * 512 * 512;
  const float* X = xf  + (size_t)bb * 512 * 96;
  const int arow = tid >> 1, ahf = tid & 1;
  const float* arp = A + (size_t)(m0 + arow) * 512 + ahf * 16;
  const int bnode = tid >> 3, bseg = tid & 7;
  const float* xp0 = X + (size_t)bnode * 96 + bseg * 12;

  float4 Ra[4], Rb[3];

#define AGG_ISSUE(c) do { \
    const float* ap = arp + (c) * 32; \
    _Pragma("unroll") for (int j = 0; j < 4; ++j) Ra[j] = *(const float4*)(ap + j * 4); \
    const float* xp = xp0 + (size_t)(c) * 32 * 96; \
    Rb[0] = *(const float4*)xp; \
    Rb[1] = *(const float4*)(xp + 4); \
    Rb[2] = *(const float4*)(xp + 8); } while (0)

#define AGG_PUT(b, d, h, l) do { \
    int off = (bnode * 2) ^ ((((d) >> 2) & 3) << 4); \
    *(u16*)((char*)&sBh[b][d][0] + off) = (h); \
    *(u16*)((char*)&sBl[b][d][0] + off) = (l); } while (0)

#define AGG_WRITE(b) do { \
    _Pragma("unroll") for (int j = 0; j < 4; ++j) { \
      ushort4 oh, ol; split4(Ra[j], oh, ol); \
      int kk = ahf * 16 + j * 4; \
      *(ushort4*)&sAh[b][arow][kk] = oh; \
      *(ushort4*)&sAl[b][arow][kk] = ol; } \
    _Pragma("unroll") for (int i = 0; i < 3; ++i) { \
      float4 v = Rb[i]; \
      int d0 = bseg * 12 + i * 4; \
      u16 h, l; \
      splitf(v.x, h, l); AGG_PUT(b, d0    , h, l); \
      splitf(v.y, h, l); AGG_PUT(b, d0 + 1, h, l); \
      splitf(v.z, h, l); AGG_PUT(b, d0 + 2, h, l); \
      splitf(v.w, h, l); AGG_PUT(b, d0 + 3, h, l); } } while (0)

  facc4 acc[2][6] = {};
  AGG_ISSUE(0); AGG_WRITE(0); AGG_ISSUE(1);
  __syncthreads();
  for (int c = 0; c < 16; ++c) {          // K = 512, chunks of 32
    int cur = c & 1;
    if (c < 15) {
      AGG_WRITE(cur ^ 1);
      if (c < 14) AGG_ISSUE(c + 2);
    }
    int kb = q * 8;
    bfrag a0h = *(const bfrag*)&sAh[cur][wave * 32 + l15][kb];
    bfrag a0l = *(const bfrag*)&sAl[cur][wave * 32 + l15][kb];
    bfrag a1h = *(const bfrag*)&sAh[cur][wave * 32 + 16 + l15][kb];
    bfrag a1l = *(const bfrag*)&sAl[cur][wave * 32 + 16 + l15][kb];
    #pragma unroll
    for (int nt = 0; nt < 6; ++nt) {
      int d = nt * 16 + l15;
      int off = (q * 16) ^ (((d >> 2) & 3) << 4);
      bfrag bh = *(const bfrag*)((const char*)&sBh[cur][d][0] + off);
      bfrag bl = *(const bfrag*)((const char*)&sBl[cur][d][0] + off);
      acc[0][nt] = MFMA(a0h, bh, acc[0][nt], 0, 0, 0);
      acc[0][nt] = MFMA(a0h, bl, acc[0][nt], 0, 0, 0);
      acc[0][nt] = MFMA(a0l, bh, acc[0][nt], 0, 0, 0);
      acc[1][nt] = MFMA(a1h, bh, acc[1][nt], 0, 0, 0);
      acc[1][nt] = MFMA(a1h, bl, acc[1][nt], 0, 0, 0);
      acc[1][nt] = MFMA(a1l, bh, acc[1][nt], 0, 0, 0);
    }
    __syncthreads();
  }
  #pragma unroll
  for (int mt = 0; mt < 2; ++mt)
  #pragma unroll
  for (int rg = 0; rg < 4; ++rg) {
    int row = m0 + wave * 32 + mt * 16 + q * 4 + rg;
    size_t grow = (size_t)bb * 512 + row;
    #pragma unroll
    for (int nt = 0; nt < 6; ++nt) {
      int col = nt * 16 + l15;
      af[grow * 96 + col] = acc[mt][nt][rg];
    }
  }
}

// ---------------- fused GRU ----------------------------------------------------
// GEMM1 computes az, ar AND the a@Wh0 part of ah (same A chunks, bit-identical
// accumulation order) -> GEMM2 is only rx@Wh1 read from LDS (no af re-read).
// launch_bounds(256,2): 144 accumulator VGPRs + staging need ~230 regs; cap 256
// matches the LDS-limited 2 waves/SIMD and kills the round-1 spills
// (VGPR_Count=144, 24 MB/dispatch scratch stores).  Gate phase stashes xv in
// the dead ar accumulator -> epilogue's 50 MB xf re-read eliminated.
__global__ __launch_bounds__(256, 2) void k_gru(const float* af, float* xf,
    const u16* __restrict__ wzrTh, const u16* __restrict__ wzrTl,
    const u16* __restrict__ whTh,  const u16* __restrict__ whTl,
    const float* __restrict__ bias, const float* __restrict__ mask,
    float* outp, const int last)
{
  // pool carve:
  //  GEMM1: sAh[128][40]@0  sAl@10240  sBh[288][40]@20480  sBl@43520  (66560)
  //  gates: sRxh[128][104]@0  sRxl@26624                              (53248)
  //  GEMM2: sB2h[96][40]@53248  sB2l@60928                            (68608)
  __shared__ __align__(16) char pool[68608];
  u16 (*sAh)[40]   = (u16(*)[40])(pool);
  u16 (*sAl)[40]   = (u16(*)[40])(pool + 10240);
  u16 (*sBh)[40]   = (u16(*)[40])(pool + 20480);   // rows: z 0-95, r 96-191, h0 192-287
  u16 (*sBl)[40]   = (u16(*)[40])(pool + 43520);
  u16 (*sRxh)[104] = (u16(*)[104])(pool);
  u16 (*sRxl)[104] = (u16(*)[104])(pool + 26624);
  u16 (*sB2h)[40]  = (u16(*)[40])(pool + 53248);
  u16 (*sB2l)[40]  = (u16(*)[40])(pool + 60928);

  const int tid = threadIdx.x;
  const int wave = tid >> 6, lane = tid & 63, q = lane >> 4, l15 = lane & 15;
  const int m0 = blockIdx.x * 128;
  const int arow = tid >> 1, ahf = tid & 1;

  float4 Ra[4];
  uint4  Rz[3], Rr[3];

#define GRU_ISSUE_A(c) do { \
    const float* base = ((c) < 3 ? af : xf) + (size_t)(m0 + arow) * 96 + ((c) % 3) * 32 + ahf * 16; \
    _Pragma("unroll") for (int j = 0; j < 4; ++j) Ra[j] = *(const float4*)(base + j * 4); \
  } while (0)

#define GRU_ISSUE_B(c) do { \
    int kw = (c) * 32; \
    _Pragma("unroll") for (int i = 0; i < 3; ++i) { \
      int idx = tid + 256 * i; \
      int half = idx >= 384; \
      int rr = idx - half * 384; \
      size_t o = (size_t)(rr >> 2) * 192 + kw + (rr & 3) * 8; \
      const u16* sb = half ? wzrTl : wzrTh; \
      Rz[i] = *(const uint4*)(sb + o); \
      Rr[i] = *(const uint4*)(sb + 18432 + o); \
    } } while (0)

#define GRU_WRITE_1(kw, withH) do { \
    _Pragma("unroll") for (int j = 0; j < 4; ++j) { \
      ushort4 oh, ol; split4(Ra[j], oh, ol); \
      int kk = ahf * 16 + j * 4; \
      *(ushort4*)&sAh[arow][kk] = oh; \
      *(ushort4*)&sAl[arow][kk] = ol; } \
    _Pragma("unroll") for (int i = 0; i < 3; ++i) { \
      int idx = tid + 256 * i; \
      int half = idx >= 384; \
      int rr = idx - half * 384; \
      int n = rr >> 2, sg = rr & 3; \
      if (half) { *(uint4*)&sBl[n][sg * 8] = Rz[i]; *(uint4*)&sBl[96 + n][sg * 8] = Rr[i]; } \
      else      { *(uint4*)&sBh[n][sg * 8] = Rz[i]; *(uint4*)&sBh[96 + n][sg * 8] = Rr[i]; } \
      if (withH) { \
        size_t o = (size_t)n * 192 + (kw) + sg * 8; \
        uint4 th = *(const uint4*)((half ? whTl : whTh) + o); \
        if (half) *(uint4*)&sBl[192 + n][sg * 8] = th; \
        else      *(uint4*)&sBh[192 + n][sg * 8] = th; \
      } } } while (0)

  // ---- GEMM1: az, ar over K=192; ah gets a@Wh0 for chunks 0..2 ----
  facc4 az[2][6] = {}, ar[2][6] = {}, ah[2][6] = {};
  GRU_ISSUE_A(0); GRU_ISSUE_B(0);
  GRU_WRITE_1(0, 1);
  __syncthreads();
  for (int c = 0; c < 6; ++c) {
    if (c < 5) { GRU_ISSUE_A(c + 1); GRU_ISSUE_B(c + 1); }
    int kb = q * 8;
    bfrag a0h = *(const bfrag*)&sAh[wave * 32 + l15][kb];
    bfrag a0l = *(const bfrag*)&sAl[wave * 32 + l15][kb];
    bfrag a1h = *(const bfrag*)&sAh[wave * 32 + 16 + l15][kb];
    bfrag a1l = *(const bfrag*)&sAl[wave * 32 + 16 + l15][kb];
    #pragma unroll
    for (int nt = 0; nt < 6; ++nt) {
      bfrag bh = *(const bfrag*)&sBh[nt * 16 + l15][kb];
      bfrag bl = *(const bfrag*)&sBl[nt * 16 + l15][kb];
      az[0][nt] = MFMA(a0h, bh, az[0][nt], 0, 0, 0);
      az[0][nt] = MFMA(a0h, bl, az[0][nt], 0, 0, 0);
      az[0][nt] = MFMA(a0l, bh, az[0][nt], 0, 0, 0);
      az[1][nt] = MFMA(a1h, bh, az[1][nt], 0, 0, 0);
      az[1][nt] = MFMA(a1h, bl, az[1][nt], 0, 0, 0);
      az[1][nt] = MFMA(a1l, bh, az[1][nt], 0, 0, 0);
      bfrag ch = *(const bfrag*)&sBh[96 + nt * 16 + l15][kb];
      bfrag cl = *(const bfrag*)&sBl[96 + nt * 16 + l15][kb];
      ar[0][nt] = MFMA(a0h, ch, ar[0][nt], 0, 0, 0);
      ar[0][nt] = MFMA(a0h, cl, ar[0][nt], 0, 0, 0);
      ar[0][nt] = MFMA(a0l, ch, ar[0][nt], 0, 0, 0);
      ar[1][nt] = MFMA(a1h, ch, ar[1][nt], 0, 0, 0);
      ar[1][nt] = MFMA(a1h, cl, ar[1][nt], 0, 0, 0);
      ar[1][nt] = MFMA(a1l, ch, ar[1][nt], 0, 0, 0);
    }
    if (c < 3) {
      #pragma unroll
      for (int nt = 0; nt < 6; ++nt) {
        bfrag dh = *(const bfrag*)&sBh[192 + nt * 16 + l15][kb];
        bfrag dl = *(const bfrag*)&sBl[192 + nt * 16 + l15][kb];
        ah[0][nt] = MFMA(a0h, dh, ah[0][nt], 0, 0, 0);
        ah[0][nt] = MFMA(a0h, dl, ah[0][nt], 0, 0, 0);
        ah[0][nt] = MFMA(a0l, dh, ah[0][nt], 0, 0, 0);
        ah[1][nt] = MFMA(a1h, dh, ah[1][nt], 0, 0, 0);
        ah[1][nt] = MFMA(a1h, dl, ah[1][nt], 0, 0, 0);
        ah[1][nt] = MFMA(a1l, dh, ah[1][nt], 0, 0, 0);
      }
    }
    __syncthreads();
    if (c < 5) { GRU_WRITE_1((c + 1) * 32, (c + 1) < 3); __syncthreads(); }
  }

  // ---- gates: z kept fp32 in az; xv stashed in ar; rx -> sRx (pool reuse) ----
  #pragma unroll
  for (int mt = 0; mt < 2; ++mt)
  #pragma unroll
  for (int rg = 0; rg < 4; ++rg) {
    int row = wave * 32 + mt * 16 + q * 4 + rg;
    int grow = m0 + row;
    #pragma unroll
    for (int nt = 0; nt < 6; ++nt) {
      int col = nt * 16 + l15;
      float vz = az[mt][nt][rg] + bias[96 + col];
      float vr = ar[mt][nt][rg] + bias[192 + col];
      float z = 1.f / (1.f + __expf(-vz));
      float r = 1.f / (1.f + __expf(-vr));
      az[mt][nt][rg] = z;
      float xv = xf[(size_t)grow * 96 + col];
      ar[mt][nt][rg] = xv;                      // stash xv for epilogue
      float rx = r * xv;
      u16 h, l; splitf(rx, h, l);
      sRxh[row][col] = h;
      sRxl[row][col] = l;
    }
  }

  // ---- GEMM2: ah += rx @ Wh1 (A from LDS only; 3 chunks) ----
  uint4 R2[3];
#define GRU_ISSUE_B2(c) do { \
    _Pragma("unroll") for (int i = 0; i < 3; ++i) { \
      int idx = tid + 256 * i; \
      int half = idx >= 384; \
      int rr = idx - half * 384; \
      size_t o = (size_t)(rr >> 2) * 192 + 96 + (c) * 32 + (rr & 3) * 8; \
      R2[i] = *(const uint4*)((half ? whTl : whTh) + o); \
    } } while (0)
#define GRU_WRITE_B2() do { \
    _Pragma("unroll") for (int i = 0; i < 3; ++i) { \
      int idx = tid + 256 * i; \
      int half = idx >= 384; \
      int rr = idx - half * 384; \
      int n = rr >> 2, sg = rr & 3; \
      if (half) *(uint4*)&sB2l[n][sg * 8] = R2[i]; \
      else      *(uint4*)&sB2h[n][sg * 8] = R2[i]; \
    } } while (0)

  GRU_ISSUE_B2(0); GRU_WRITE_B2();
  __syncthreads();                        // publishes sRx + sB2
  for (int c = 0; c < 3; ++c) {
    if (c < 2) GRU_ISSUE_B2(c + 1);
    int kb = c * 32 + q * 8;
    bfrag a0h = *(const bfrag*)&sRxh[wave * 32 + l15][kb];
    bfrag a0l = *(const bfrag*)&sRxl[wave * 32 + l15][kb];
    bfrag a1h = *(const bfrag*)&sRxh[wave * 32 + 16 + l15][kb];
    bfrag a1l = *(const bfrag*)&sRxl[wave * 32 + 16 + l15][kb];
    #pragma unroll
    for (int nt = 0; nt < 6; ++nt) {
      bfrag bh = *(const bfrag*)&sB2h[nt * 16 + l15][q * 8];
      bfrag bl = *(const bfrag*)&sB2l[nt * 16 + l15][q * 8];
      ah[0][nt] = MFMA(a0h, bh, ah[0][nt], 0, 0, 0);
      ah[0][nt] = MFMA(a0h, bl, ah[0][nt], 0, 0, 0);
      ah[0][nt] = MFMA(a0l, bh, ah[0][nt], 0, 0, 0);
      ah[1][nt] = MFMA(a1h, bh, ah[1][nt], 0, 0, 0);
      ah[1][nt] = MFMA(a1h, bl, ah[1][nt], 0, 0, 0);
      ah[1][nt] = MFMA(a1l, bh, ah[1][nt], 0, 0, 0);
    }
    __syncthreads();
    if (c < 2) { GRU_WRITE_B2(); __syncthreads(); }
  }

  // ---- gate epilogue: out = x + z*(relu(mask*(h_pre+bh)) - x); xv from ar ----
  #pragma unroll
  for (int mt = 0; mt < 2; ++mt)
  #pragma unroll
  for (int rg = 0; rg < 4; ++rg) {
    int row = m0 + wave * 32 + mt * 16 + q * 4 + rg;
    float mk = mask[row];
    #pragma unroll
    for (int nt = 0; nt < 6; ++nt) {
      int col = nt * 16 + l15;
      size_t idx = (size_t)row * 96 + col;
      float pre = ah[mt][nt][rg] + bias[288 + col];
      float hv  = fmaxf(mk * pre, 0.f);
      float zv  = az[mt][nt][rg];
      float xv  = ar[mt][nt][rg];
      float o   = xv + zv * (hv - xv);
      if (last) outp[idx] = o;
      else      xf[idx]   = o;
    }
  }
}

extern "C" void kernel_launch(void* const* d_in, const int* in_sizes, int n_in,
                              void* d_out, int out_size, void* d_ws, size_t ws_size,
                              hipStream_t stream)
{
  const float* x    = (const float*)d_in[0];
  const float* adj  = (const float*)d_in[1];
  const float* mask = (const float*)d_in[2];
  const float* Wenc = (const float*)d_in[3];
  const float* benc = (const float*)d_in[4];
  const float* Wz0  = (const float*)d_in[5];
  const float* Wz1  = (const float*)d_in[6];
  const float* Wr0  = (const float*)d_in[7];
  const float* Wr1  = (const float*)d_in[8];
  const float* Wh0  = (const float*)d_in[9];
  const float* Wh1  = (const float*)d_in[10];
  const float* bz0  = (const float*)d_in[11];
  const float* bz1  = (const float*)d_in[12];
  const float* br0  = (const float*)d_in[13];
  const float* br1  = (const float*)d_in[14];
  const float* bh0  = (const float*)d_in[15];
  const float* bh1  = (const float*)d_in[16];

  char* ws = (char*)d_ws;
  const size_t NEL = (size_t)MROWS * DD;            // 12,582,912
  float* xf   = (float*)(ws);                       // 50,331,648 B
  char*  wb   = ws + 4 * NEL;
  u16* wencTh = (u16*)(wb);                         // 73,728 B
  u16* wencTl = (u16*)(wb + 73728);
  u16* wzrTh  = (u16*)(wb + 147456);                // 73,728 B
  u16* wzrTl  = (u16*)(wb + 221184);
  u16* whTh   = (u16*)(wb + 294912);                // 36,864 B
  u16* whTl   = (u16*)(wb + 331776);
  float* bias = (float*)(wb + 368640);              // 1,536 B

  float* af   = (float*)d_out;                      // a-buffer aliases d_out
  float* outp = (float*)d_out;

  k_prep<<<362, 256, 0, stream>>>(Wenc, benc, Wz0, Wz1, Wr0, Wr1, Wh0, Wh1,
                                  bz0, bz1, br0, br1, bh0, bh1,
                                  wencTh, wencTl, wzrTh, wzrTl, whTh, whTl, bias);
  k_enc<<<dim3(MROWS / 128), 256, 0, stream>>>(x, mask, wencTh, wencTl, bias, xf);
  for (int s = 0; s < 2; ++s) {
    int last = (s == 1);
    k_agg<<<dim3(4, 256), 256, 0, stream>>>(adj, xf, af);
    k_gru<<<dim3(MROWS / 128), 256, 0, stream>>>(af, xf, wzrTh, wzrTl, whTh, whTl,
                                                 bias, mask, outp, last);
  }
}